// Round 1
// baseline (2059.490 us; speedup 1.0000x reference)
//
#include <hip/hip_runtime.h>
#include <math.h>

#define N_NODES 50000
#define N_EDGES 500000
#define N_GRAPHS 2048
#define HID 128
#define EDIM 12
#define NLAYERS 8
#define EPS_BN 1e-5f

// ---------------- CSR build ----------------
__global__ void zero_kernel(int* deg, int* cursor, float* stats) {
  int i = blockIdx.x * 256 + threadIdx.x;
  if (i < N_NODES) { deg[i] = 0; cursor[i] = 0; }
  if (i < NLAYERS * 256) stats[i] = 0.f;
}

__global__ void count_kernel(const int* __restrict__ dst, int* __restrict__ deg) {
  int e = blockIdx.x * 256 + threadIdx.x;
  if (e < N_EDGES) atomicAdd(&deg[dst[e]], 1);
}

__global__ void scan1_kernel(int* __restrict__ off, int* __restrict__ bsum) {
  __shared__ int s[256];
  int t = threadIdx.x; int n = blockIdx.x * 256 + t;
  int x = (n < N_NODES) ? off[n] : 0;
  s[t] = x; __syncthreads();
  for (int o = 1; o < 256; o <<= 1) {
    int v = (t >= o) ? s[t - o] : 0;
    __syncthreads(); s[t] += v; __syncthreads();
  }
  if (n < N_NODES) off[n] = s[t] - x;   // block-local exclusive
  if (t == 255) bsum[blockIdx.x] = s[255];
}

__global__ void scan2_kernel(int* __restrict__ bsum, int nb) {
  __shared__ int s[256];
  int t = threadIdx.x;
  int x = (t < nb) ? bsum[t] : 0;
  s[t] = x; __syncthreads();
  for (int o = 1; o < 256; o <<= 1) {
    int v = (t >= o) ? s[t - o] : 0;
    __syncthreads(); s[t] += v; __syncthreads();
  }
  if (t < nb) bsum[t] = s[t] - x;       // exclusive
}

__global__ void scan3_kernel(int* __restrict__ off, const int* __restrict__ bsum) {
  int t = threadIdx.x; int n = blockIdx.x * 256 + t;
  if (n < N_NODES) off[n] += bsum[blockIdx.x];
  if (n == 0 && blockIdx.x == 0) off[N_NODES] = N_EDGES;
}

__global__ void scatter_kernel(const int* __restrict__ dst, const int* __restrict__ off,
                               int* __restrict__ cursor, int* __restrict__ elist) {
  int e = blockIdx.x * 256 + threadIdx.x;
  if (e < N_EDGES) {
    int d = dst[e];
    int p = atomicAdd(&cursor[d], 1);
    elist[off[d] + p] = e;
  }
}

// ---------------- input projection ----------------
__global__ void inproj_kernel(const float* __restrict__ x, const float* __restrict__ Win,
                              const float* __restrict__ b_in, float* __restrict__ h) {
  __shared__ float xs[44];
  int t = threadIdx.x;
  int n0 = blockIdx.x * 2;
  if (t < 44) {
    int n = n0 + t / 22;
    xs[t] = (n < N_NODES) ? x[n0 * 22 + t] : 0.f;
  }
  __syncthreads();
  int c = t & 127, half = t >> 7;
  int n = n0 + half;
  if (n < N_NODES) {
    float acc = b_in[c];
#pragma unroll
    for (int k = 0; k < 22; k++) acc = fmaf(xs[half * 22 + k], Win[k * HID + c], acc);
    h[n * HID + c] = fmaxf(acc, 0.f);
  }
}

// ---------------- generic f32 GEMM: C[nrows,CO] = A[nrows,128] @ W[128,CO] (+bias) ----------------
template <int CO, bool BIAS, bool RELU>
__global__ __launch_bounds__(256) void gemm_kernel(const float* __restrict__ A,
                                                   const float* __restrict__ W,
                                                   const float* __restrict__ bias,
                                                   float* __restrict__ C, int nrows) {
  __shared__ float As[32 * 128];
  constexpr int CW = CO / 32;
  int t = threadIdx.x;
  int brow = blockIdx.x * 32;
#pragma unroll
  for (int i = 0; i < 4; i++) {
    int f = t + i * 256;
    int r = f >> 5, cf = (f & 31) << 2;
    int g = brow + r;
    float4 v = (g < nrows) ? *(const float4*)&A[g * 128 + cf] : make_float4(0.f, 0.f, 0.f, 0.f);
    *(float4*)&As[r * 128 + cf] = v;
  }
  __syncthreads();
  int cgrp = t & 31, rgrp = t >> 5;
  int c0 = cgrp * CW, r0 = rgrp * 4;
  float acc[4][CW];
#pragma unroll
  for (int r = 0; r < 4; r++)
#pragma unroll
    for (int c = 0; c < CW; c++) acc[r][c] = 0.f;

  for (int k = 0; k < 128; k += 4) {
    float a[4][4];
#pragma unroll
    for (int r = 0; r < 4; r++) {
      float4 av = *(const float4*)&As[(r0 + r) * 128 + k];
      a[r][0] = av.x; a[r][1] = av.y; a[r][2] = av.z; a[r][3] = av.w;
    }
#pragma unroll
    for (int kk = 0; kk < 4; kk++) {
      float w[CW];
      if constexpr (CW == 4) {
        float4 wv = *(const float4*)&W[(k + kk) * CO + c0];
        w[0] = wv.x; w[1] = wv.y; w[2] = wv.z; w[3] = wv.w;
      } else {
        float2 wv = *(const float2*)&W[(k + kk) * CO + c0];
        w[0] = wv.x; w[1] = wv.y;
      }
#pragma unroll
      for (int r = 0; r < 4; r++)
#pragma unroll
        for (int c = 0; c < CW; c++) acc[r][c] = fmaf(a[r][kk], w[c], acc[r][c]);
    }
  }
  float b[CW];
#pragma unroll
  for (int c = 0; c < CW; c++) b[c] = BIAS ? bias[c0 + c] : 0.f;
#pragma unroll
  for (int r = 0; r < 4; r++) {
    int g = brow + r0 + r;
    if (g < nrows) {
      float o[CW];
#pragma unroll
      for (int c = 0; c < CW; c++) {
        float v = acc[r][c] + b[c];
        o[c] = RELU ? fmaxf(v, 0.f) : v;
      }
      if constexpr (CW == 4) *(float4*)&C[g * CO + c0] = *(float4*)&o[0];
      else *(float2*)&C[g * CO + c0] = *(float2*)&o[0];
    }
  }
}

// ---------------- GATv2 aggregation (one wave per destination node) ----------------
__global__ __launch_bounds__(256) void gat_kernel(
    const float* __restrict__ xl, const float* __restrict__ xr,
    const float* __restrict__ edge_attr, const int* __restrict__ src,
    const int* __restrict__ elist, const int* __restrict__ off,
    const float* __restrict__ Wel, const float* __restrict__ attl,
    const float* __restrict__ bol, float* __restrict__ out) {
  int lane = threadIdx.x & 63;
  int node = blockIdx.x * 4 + (threadIdx.x >> 6);
  if (node >= N_NODES) return;
  int c0 = lane * 2;  // channels c0, c0+1 -> same head (c0/32)

  float2 wk[12];
#pragma unroll
  for (int k = 0; k < 12; k++) wk[k] = *(const float2*)&Wel[k * HID + c0];
  float2 at = *(const float2*)&attl[c0];
  float2 xr2 = *(const float2*)&xr[node * HID + c0];

  float m = -INFINITY, den = 0.f, acc0 = 0.f, acc1 = 0.f;
  int is = off[node], ie = off[node + 1];
  for (int i = is; i < ie; i++) {
    int e = elist[i];
    int s = src[e];
    const float* ea = &edge_attr[e * EDIM];
    float4 e0 = *(const float4*)ea;
    float4 e1 = *(const float4*)(ea + 4);
    float4 e2 = *(const float4*)(ea + 8);
    float eav[12] = {e0.x, e0.y, e0.z, e0.w, e1.x, e1.y, e1.z, e1.w, e2.x, e2.y, e2.z, e2.w};
    float2 xl2 = *(const float2*)&xl[s * HID + c0];
    float ep0 = 0.f, ep1 = 0.f;
#pragma unroll
    for (int k = 0; k < 12; k++) {
      ep0 = fmaf(eav[k], wk[k].x, ep0);
      ep1 = fmaf(eav[k], wk[k].y, ep1);
    }
    float s0 = xl2.x + xr2.x + ep0; s0 = (s0 > 0.f) ? s0 : 0.2f * s0;
    float s1 = xl2.y + xr2.y + ep1; s1 = (s1 > 0.f) ? s1 : 0.2f * s1;
    float v = fmaf(s0, at.x, s1 * at.y);
    // reduce across the 16 lanes of this head (32 channels)
    v += __shfl_xor(v, 1);
    v += __shfl_xor(v, 2);
    v += __shfl_xor(v, 4);
    v += __shfl_xor(v, 8);
    // online softmax update (branchless)
    float mn = fmaxf(m, v);
    float sc = __expf(m - mn);   // exp(-inf)=0 handles the first edge
    float p = __expf(v - mn);
    den = fmaf(den, sc, p);
    acc0 = fmaf(p, xl2.x, acc0 * sc);
    acc1 = fmaf(p, xl2.y, acc1 * sc);
    m = mn;
  }
  float inv = 1.f / (den + 1e-16f);
  float2 bo2 = *(const float2*)&bol[c0];
  float2 o;
  o.x = fmaf(acc0, inv, bo2.x);
  o.y = fmaf(acc1, inv, bo2.y);
  *(float2*)&out[node * HID + c0] = o;
}

// ---------------- BatchNorm ----------------
__global__ void bnstats_kernel(const float* __restrict__ t, float* __restrict__ sums) {
  int tid = threadIdx.x;
  int c = tid & 127, half = tid >> 7;
  float s = 0.f, q = 0.f;
  for (int n = blockIdx.x * 2 + half; n < N_NODES; n += 512) {
    float v = t[n * HID + c];
    s += v; q = fmaf(v, v, q);
  }
  __shared__ float ls[256], lq[256];
  ls[tid] = s; lq[tid] = q;
  __syncthreads();
  if (tid < 128) {
    atomicAdd(&sums[c], ls[tid] + ls[tid + 128]);
    atomicAdd(&sums[128 + c], lq[tid] + lq[tid + 128]);
  }
}

__global__ void bnapply_kernel(const float* __restrict__ t, const float* __restrict__ res,
                               const float* __restrict__ sums, const float* __restrict__ gamma,
                               const float* __restrict__ beta, float* __restrict__ hout) {
  int i4 = blockIdx.x * 256 + threadIdx.x;
  if (i4 >= N_NODES * 32) return;
  int c0 = (i4 & 31) << 2;
  const float invN = 1.f / (float)N_NODES;
  float4 tv = *(const float4*)&t[i4 * 4];
  float4 sm = *(const float4*)&sums[c0];
  float4 sq = *(const float4*)&sums[128 + c0];
  float4 gm = *(const float4*)&gamma[c0];
  float4 bt = *(const float4*)&beta[c0];
  float4 rv = make_float4(0.f, 0.f, 0.f, 0.f);
  if (res) rv = *(const float4*)&res[i4 * 4];
  float4 o;
#define BN1(comp)                                                   \
  {                                                                 \
    float mu = sm.comp * invN;                                      \
    float var = sq.comp * invN - mu * mu;                           \
    float rs = rsqrtf(var + EPS_BN);                                \
    float v = (tv.comp - mu) * rs * gm.comp + bt.comp + rv.comp;    \
    o.comp = fmaxf(v, 0.f);                                         \
  }
  BN1(x) BN1(y) BN1(z) BN1(w)
#undef BN1
  *(float4*)&hout[i4 * 4] = o;
}

// ---------------- policy head (one wave per edge) ----------------
__global__ __launch_bounds__(256) void policy_kernel(
    const float* __restrict__ Ps, const float* __restrict__ Pd,
    const int* __restrict__ src, const int* __restrict__ dst,
    const float* __restrict__ edge_attr, const float* __restrict__ Wp1e,
    const float* __restrict__ bp1, const float* __restrict__ Wp2,
    const float* __restrict__ bp2, float* __restrict__ outp) {
  int lane = threadIdx.x & 63;
  int e = blockIdx.x * 4 + (threadIdx.x >> 6);
  if (e >= N_EDGES) return;
  float we[12];
#pragma unroll
  for (int k = 0; k < 12; k++) we[k] = Wp1e[k * 64 + lane];
  float b = bp1[lane], w2 = Wp2[lane];
  int s = src[e], d = dst[e];
  const float* ea = &edge_attr[e * EDIM];
  float4 e0 = *(const float4*)ea;
  float4 e1 = *(const float4*)(ea + 4);
  float4 e2 = *(const float4*)(ea + 8);
  float eav[12] = {e0.x, e0.y, e0.z, e0.w, e1.x, e1.y, e1.z, e1.w, e2.x, e2.y, e2.z, e2.w};
  float hj = Ps[s * 64 + lane] + Pd[d * 64 + lane] + b;
#pragma unroll
  for (int k = 0; k < 12; k++) hj = fmaf(eav[k], we[k], hj);
  hj = fmaxf(hj, 0.f);
  float v = hj * w2;
  v += __shfl_xor(v, 32);
  v += __shfl_xor(v, 16);
  v += __shfl_xor(v, 8);
  v += __shfl_xor(v, 4);
  v += __shfl_xor(v, 2);
  v += __shfl_xor(v, 1);
  if (lane == 0) outp[e] = v + bp2[0];
}

// ---------------- pooled mean + value head (one block per graph) ----------------
__device__ int lower_bound_dev(const int* a, int n, int key) {
  int lo = 0, hi = n;
  while (lo < hi) {
    int mid = (lo + hi) >> 1;
    if (a[mid] < key) lo = mid + 1; else hi = mid;
  }
  return lo;
}

__global__ void poolvalue_kernel(const float* __restrict__ h, const int* __restrict__ batch,
                                 const float* __restrict__ Wv1, const float* __restrict__ bv1,
                                 const float* __restrict__ Wv2, const float* __restrict__ bv2,
                                 float* __restrict__ outv) {
  __shared__ float pl[128];
  __shared__ float hd[64];
  __shared__ int range[2];
  int g = blockIdx.x, t = threadIdx.x;
  if (t == 0) {
    range[0] = lower_bound_dev(batch, N_NODES, g);
    range[1] = lower_bound_dev(batch, N_NODES, g + 1);
  }
  __syncthreads();
  int lo = range[0], hi = range[1];
  float s = 0.f;
  for (int n = lo; n < hi; n++) s += h[n * HID + t];
  float cnt = (float)(hi - lo);
  pl[t] = s / fmaxf(cnt, 1.f);
  __syncthreads();
  if (t < 64) {
    float a = bv1[t];
    for (int c = 0; c < 128; c++) a = fmaf(pl[c], Wv1[c * 64 + t], a);
    hd[t] = fmaxf(a, 0.f);
  }
  __syncthreads();
  if (t < 3) {
    float a = bv2[t];
    for (int j = 0; j < 64; j++) a = fmaf(hd[j], Wv2[j * 3 + t], a);
    outv[g * 3 + t] = a;
  }
}

// ---------------- host ----------------
extern "C" void kernel_launch(void* const* d_in, const int* in_sizes, int n_in,
                              void* d_out, int out_size, void* d_ws, size_t ws_size,
                              hipStream_t stream) {
  (void)in_sizes; (void)n_in; (void)out_size; (void)ws_size;
  const float* x    = (const float*)d_in[0];
  const int*   src  = (const int*)d_in[1];
  const int*   dst  = (const int*)d_in[2];
  const int*   batch= (const int*)d_in[3];
  const float* ea   = (const float*)d_in[4];
  const float* Win  = (const float*)d_in[5];
  const float* b_in = (const float*)d_in[6];
  const float* Wl   = (const float*)d_in[7];
  const float* bl   = (const float*)d_in[8];
  const float* Wr   = (const float*)d_in[9];
  const float* br   = (const float*)d_in[10];
  const float* We   = (const float*)d_in[11];
  const float* att  = (const float*)d_in[12];
  const float* bo   = (const float*)d_in[13];
  const float* gamma= (const float*)d_in[14];
  const float* beta = (const float*)d_in[15];
  const float* Wv1  = (const float*)d_in[16];
  const float* bv1  = (const float*)d_in[17];
  const float* Wv2  = (const float*)d_in[18];
  const float* bv2  = (const float*)d_in[19];
  const float* Wp1  = (const float*)d_in[20];
  const float* bp1  = (const float*)d_in[21];
  const float* Wp2  = (const float*)d_in[22];
  const float* bp2  = (const float*)d_in[23];

  float* outv = (float*)d_out;                      // [G,3]
  float* outp = outv + (size_t)N_GRAPHS * 3;        // [E]

  float* hA    = (float*)d_ws;
  float* hB    = hA  + (size_t)N_NODES * HID;
  float* tmp   = hB  + (size_t)N_NODES * HID;
  float* xlb   = tmp + (size_t)N_NODES * HID;
  float* xrb   = xlb + (size_t)N_NODES * HID;
  float* stats = xrb + (size_t)N_NODES * HID;
  int* off    = (int*)(stats + NLAYERS * 256);
  int* cursor = off + (N_NODES + 1);
  int* bsum   = cursor + N_NODES;
  int* elist  = bsum + 256;

  const int NB = (N_NODES + 255) / 256;
  const int EB = (N_EDGES + 255) / 256;

  zero_kernel<<<NB, 256, 0, stream>>>(off, cursor, stats);
  count_kernel<<<EB, 256, 0, stream>>>(dst, off);
  scan1_kernel<<<NB, 256, 0, stream>>>(off, bsum);
  scan2_kernel<<<1, 256, 0, stream>>>(bsum, NB);
  scan3_kernel<<<NB, 256, 0, stream>>>(off, bsum);
  scatter_kernel<<<EB, 256, 0, stream>>>(dst, off, cursor, elist);
  inproj_kernel<<<N_NODES / 2, 256, 0, stream>>>(x, Win, b_in, hA);

  const int GB = (N_NODES + 31) / 32;
  const int GATB = (N_NODES + 3) / 4;
  const int APB = (N_NODES * 32 + 255) / 256;

  for (int b2 = 0; b2 < 4; b2++) {
    int i = 2 * b2, j = i + 1;
    // layer i: hA -> hB
    gemm_kernel<128, true, false><<<GB, 256, 0, stream>>>(hA, Wl + (size_t)i * HID * HID, bl + i * HID, xlb, N_NODES);
    gemm_kernel<128, true, false><<<GB, 256, 0, stream>>>(hA, Wr + (size_t)i * HID * HID, br + i * HID, xrb, N_NODES);
    gat_kernel<<<GATB, 256, 0, stream>>>(xlb, xrb, ea, src, elist, off,
                                         We + (size_t)i * EDIM * HID, att + (size_t)i * HID,
                                         bo + (size_t)i * HID, tmp);
    bnstats_kernel<<<256, 256, 0, stream>>>(tmp, stats + i * 256);
    bnapply_kernel<<<APB, 256, 0, stream>>>(tmp, nullptr, stats + i * 256, gamma + i * HID, beta + i * HID, hB);
    // layer j: hB -> hA (residual = hA)
    gemm_kernel<128, true, false><<<GB, 256, 0, stream>>>(hB, Wl + (size_t)j * HID * HID, bl + j * HID, xlb, N_NODES);
    gemm_kernel<128, true, false><<<GB, 256, 0, stream>>>(hB, Wr + (size_t)j * HID * HID, br + j * HID, xrb, N_NODES);
    gat_kernel<<<GATB, 256, 0, stream>>>(xlb, xrb, ea, src, elist, off,
                                         We + (size_t)j * EDIM * HID, att + (size_t)j * HID,
                                         bo + (size_t)j * HID, tmp);
    bnstats_kernel<<<256, 256, 0, stream>>>(tmp, stats + j * 256);
    bnapply_kernel<<<APB, 256, 0, stream>>>(tmp, hA, stats + j * 256, gamma + j * HID, beta + j * HID, hA);
  }

  // policy head: Psrc/Pdst node projections reuse xlb
  float* Ps = xlb;
  float* Pd = xlb + (size_t)N_NODES * 64;
  gemm_kernel<64, false, false><<<GB, 256, 0, stream>>>(hA, Wp1, nullptr, Ps, N_NODES);
  gemm_kernel<64, false, false><<<GB, 256, 0, stream>>>(hA, Wp1 + 128 * 64, nullptr, Pd, N_NODES);
  policy_kernel<<<(N_EDGES + 3) / 4, 256, 0, stream>>>(Ps, Pd, src, dst, ea,
                                                       Wp1 + 256 * 64, bp1, Wp2, bp2, outp);
  poolvalue_kernel<<<N_GRAPHS, 128, 0, stream>>>(hA, batch, Wv1, bv1, Wv2, bv2, outv);
}